// Round 8
// baseline (289.262 us; speedup 1.0000x reference)
//
#include <hip/hip_runtime.h>
#include <stdint.h>

#define N_NODES 50000
#define E_EDGES 600000
#define D 128
#define R_REL 8
#define B_BASES 10
#define RN (R_REL * N_NODES)

typedef __attribute__((ext_vector_type(8))) short bf16x8;
typedef __attribute__((ext_vector_type(4))) float f32x4;

__device__ __forceinline__ short f2b(float f) {
    uint32_t u = __float_as_uint(f);
    u += 0x7fff + ((u >> 16) & 1);   // RNE
    return (short)(u >> 16);
}
__device__ __forceinline__ float b2f(uint16_t u) {
    return __uint_as_float((uint32_t)u << 16);
}

// async 16B global->LDS DMA. LDS dest must be wave-uniform; lane i deposits at
// dest + i*16B. Source is per-lane (pre-swizzle there, rule #21).
__device__ __forceinline__ void gload_lds16(const void* g, void* l) {
    __builtin_amdgcn_global_load_lds(
        (const __attribute__((address_space(1))) void*)g,
        (__attribute__((address_space(3))) void*)l, 16, 0, 0);
}

// ---- front: x->bf16 convert + (dst,rel) histogram + weight prep, one launch ----
__global__ __launch_bounds__(256) void k_front(const float* __restrict__ x,
                                               unsigned short* __restrict__ xb,
                                               const int* __restrict__ dst,
                                               const int* __restrict__ et,
                                               int* __restrict__ cntr,
                                               const float* __restrict__ basis,
                                               const float* __restrict__ comp,
                                               const float* __restrict__ root,
                                               const float* __restrict__ wrel,
                                               const float* __restrict__ wroot,
                                               short* __restrict__ wt,
                                               short* __restrict__ wrel_b,
                                               short* __restrict__ wroot_b) {
    const int XB_N = N_NODES * D / 8;   // 800000
    int tid = blockIdx.x * 256 + threadIdx.x;
    if (tid < XB_N) {
        const float4* s = (const float4*)x + (size_t)tid * 2;
        float4 v0 = s[0], v1 = s[1];
        union { uint4 u; unsigned short h[8]; } pk;
        pk.h[0] = (unsigned short)f2b(v0.x); pk.h[1] = (unsigned short)f2b(v0.y);
        pk.h[2] = (unsigned short)f2b(v0.z); pk.h[3] = (unsigned short)f2b(v0.w);
        pk.h[4] = (unsigned short)f2b(v1.x); pk.h[5] = (unsigned short)f2b(v1.y);
        pk.h[6] = (unsigned short)f2b(v1.z); pk.h[7] = (unsigned short)f2b(v1.w);
        ((uint4*)xb)[tid] = pk.u;
    } else if (tid < XB_N + E_EDGES) {
        int e = tid - XB_N;
        atomicAdd(&cntr[dst[e] * R_REL + et[e]], 1);
    } else {
        int t2 = tid - XB_N - E_EDGES;
        if (t2 < 9 * D * D) {
            int s = t2 >> 14;
            int rem = t2 & 16383;
            int j = rem >> 7, i = rem & 127;
            float v;
            if (s < 8) {
                v = 0.f;
#pragma unroll
                for (int b = 0; b < B_BASES; b++)
                    v += comp[s * B_BASES + b] * basis[b * D * D + i * D + j];
            } else {
                v = root[i * D + j];
            }
            wt[t2] = f2b(v);
        } else {
            int t3 = t2 - 9 * D * D;
            if (t3 < D * D) {
                wrel_b[t3]  = f2b(wrel[t3]);
                wroot_b[t3] = f2b(wroot[t3]);
            }
        }
    }
}

// ---- shuffle-based block scan (1024 thr); doubles as level-2 when bsum==null ----
__device__ __forceinline__ int wave_scan_incl(int v) {
    int lane = threadIdx.x & 63;
#pragma unroll
    for (int off = 1; off < 64; off <<= 1) {
        int n = __shfl_up(v, off, 64);
        if (lane >= off) v += n;
    }
    return v;
}

__global__ __launch_bounds__(1024) void k_scan_a(const int* __restrict__ in,
                                                 int* __restrict__ out,
                                                 int* __restrict__ bsum, int n) {
    __shared__ int wsum[16];
    int t = threadIdx.x, lane = t & 63, wid = t >> 6;
    int g = blockIdx.x * 1024 + t;
    int v = (g < n) ? in[g] : 0;
    int isc = wave_scan_incl(v);
    if (lane == 63) wsum[wid] = isc;
    __syncthreads();
    if (wid == 0) {
        int wv = (lane < 16) ? wsum[lane] : 0;
        int wsc = wave_scan_incl(wv);
        if (lane < 16) wsum[lane] = wsc - wv;
    }
    __syncthreads();
    if (g < n) out[g] = wsum[wid] + isc - v;
    if (t == 1023 && bsum) bsum[blockIdx.x] = wsum[15] + isc;
}

__global__ __launch_bounds__(1024) void k_scan_c(int* __restrict__ out,
                                                 const int* __restrict__ bsum, int n) {
    int g = blockIdx.x * 1024 + threadIdx.x;
    if (g < n) out[g] += bsum[blockIdx.x];
}

// ---- bucket: es1[pos] = src, sorted by (dst,rel); bumps seg_off to segment ENDS ----
__global__ __launch_bounds__(256) void k_bucket(const int* __restrict__ src,
                                                const int* __restrict__ dst,
                                                const int* __restrict__ et,
                                                int* __restrict__ seg_off,
                                                int* __restrict__ es1) {
    int e = blockIdx.x * 256 + threadIdx.x;
    if (e >= E_EDGES) return;
    int key = dst[e] * R_REL + et[e];
    int pos = atomicAdd(&seg_off[key], 1);
    es1[pos] = src[e];
}

// ---- per-(dst,rel) mean of xb[src] -> mx bf16, S-MAJOR: mx[rel][dst][D]. ----
__global__ __launch_bounds__(256) void k_aggmean(const unsigned short* __restrict__ xb,
                                                 const int* __restrict__ es1,
                                                 const int* __restrict__ seg_off,
                                                 unsigned short* __restrict__ mx) {
    int t = threadIdx.x;
    int sw = t >> 4, l = t & 15;
    int k = blockIdx.x * 16 + sw;
    if (k >= RN) return;
    int start = (k == 0) ? 0 : seg_off[k - 1];
    int end = seg_off[k];
    float ax[8];
#pragma unroll
    for (int q = 0; q < 8; q++) ax[q] = 0.f;
    size_t loff = (size_t)l * 8;
    int pos = start;
    for (; pos + 2 <= end; pos += 2) {
        int s0 = es1[pos], s1 = es1[pos + 1];
        uint4 v0 = *(const uint4*)(xb + (size_t)s0 * D + loff);
        uint4 v1 = *(const uint4*)(xb + (size_t)s1 * D + loff);
        const uint32_t* w0 = (const uint32_t*)&v0;
        const uint32_t* w1 = (const uint32_t*)&v1;
#pragma unroll
        for (int q = 0; q < 4; q++) {
            ax[q * 2]     += b2f((uint16_t)w0[q]) + b2f((uint16_t)w1[q]);
            ax[q * 2 + 1] += b2f((uint16_t)(w0[q] >> 16)) + b2f((uint16_t)(w1[q] >> 16));
        }
    }
    if (pos < end) {
        int s0 = es1[pos];
        uint4 v0 = *(const uint4*)(xb + (size_t)s0 * D + loff);
        const uint32_t* w0 = (const uint32_t*)&v0;
#pragma unroll
        for (int q = 0; q < 4; q++) {
            ax[q * 2]     += b2f((uint16_t)w0[q]);
            ax[q * 2 + 1] += b2f((uint16_t)(w0[q] >> 16));
        }
    }
    float nm = (end > start) ? 1.f / (float)(end - start) : 0.f;
    union { uint4 u; unsigned short h[8]; } pk;
#pragma unroll
    for (int q = 0; q < 8; q++) pk.h[q] = (unsigned short)f2b(ax[q] * nm);
    // s-major: k = d*8+r  ->  row = r*N + d
    size_t krow = (size_t)(k & 7) * N_NODES + (size_t)(k >> 3);
    *(uint4*)(mx + krow * D + loff) = pk.u;
}

// ---- h1 GEMM v7: r6 clean skeleton (8 waves/512thr, dbuf 64KB, 1 barrier/step)
// with ASYNC W staging: global_load_lds width=16, linear LDS dest + pre-swizzled
// global source (rule #21/m173) so the XOR read pattern is unchanged.
// DO NOT restructure the loop (r1-r4 spill history: VGPR~68 + phantom WRITE). ----
__global__ __launch_bounds__(512) void k_h1_gemm(const unsigned short* __restrict__ mx,
                                                 const unsigned short* __restrict__ xb,
                                                 const short* __restrict__ wt,
                                                 const float* __restrict__ bias1,
                                                 unsigned short* __restrict__ h1b) {
    __shared__ short ws[2][128 * 128];
    int t = threadIdx.x;
    int wave = t >> 6, lane = t & 63, quad = lane >> 4, l16 = lane & 15;
    int mw = wave & 3;        // row group: rows mw*32 .. mw*32+31
    int nw = wave >> 2;       // column half: cols nw*64 .. nw*64+63
    int base = blockIdx.x * 128;
    int n0 = base + mw * 32 + l16;
    int n1 = n0 + 16;
    int nc0 = n0 < N_NODES ? n0 : N_NODES - 1;
    int nc1 = n1 < N_NODES ? n1 : N_NODES - 1;

    auto aptr = [&](int nc, int s) -> const unsigned short* {
        return (s < 8) ? mx + ((size_t)s * N_NODES + nc) * D : xb + (size_t)nc * D;
    };

    // W staging geometry: wave covers rows wave*16 .. +15 in 4 DMA instrs.
    // Lane (quad,l16) -> LDS row r0+quad chunk l16 (linear dest); source chunk
    // is l16^(row&15) so that W[row][c] lands at chunk c^(row&15) (read swizzle).
    int swz[4];
#pragma unroll
    for (int i = 0; i < 4; i++) {
        int row = wave * 16 + i * 4 + quad;
        swz[i] = row * D + ((l16 ^ (row & 15)) << 3);
    }

    // prologue: async-stage W0 -> ws[0]; A(0),A(1) -> regs
#pragma unroll
    for (int i = 0; i < 4; i++)
        gload_lds16(wt + swz[i], &ws[0][(wave * 16 + i * 4) * 128]);

    uint4 aReg[2][2][4];   // [parity][tile][kc]
#pragma unroll
    for (int kc = 0; kc < 4; kc++) {
        int co = (kc * 4 + quad) * 8;
        aReg[0][0][kc] = *(const uint4*)(aptr(nc0, 0) + co);
        aReg[0][1][kc] = *(const uint4*)(aptr(nc1, 0) + co);
        aReg[1][0][kc] = *(const uint4*)(aptr(nc0, 1) + co);
        aReg[1][1][kc] = *(const uint4*)(aptr(nc1, 1) + co);
    }
    __syncthreads();

    f32x4 acc[2][4];
#pragma unroll
    for (int tl = 0; tl < 2; tl++)
#pragma unroll
        for (int jt = 0; jt < 4; jt++) acc[tl][jt] = (f32x4){0.f, 0.f, 0.f, 0.f};

    for (int s = 0; s < 9; s++) {
        int cur = s & 1;
        if (s + 1 < 9) {   // async-stage W_{s+1} into the other buffer
            const short* wb = wt + (size_t)(s + 1) * D * D;
#pragma unroll
            for (int i = 0; i < 4; i++)
                gload_lds16(wb + swz[i], &ws[cur ^ 1][(wave * 16 + i * 4) * 128]);
        }
#pragma unroll
        for (int kc = 0; kc < 4; kc++) {
            int c0 = kc * 4 + quad;
            bf16x8 a0 = *(bf16x8*)&aReg[cur][0][kc];
            bf16x8 a1 = *(bf16x8*)&aReg[cur][1][kc];
#pragma unroll
            for (int jt = 0; jt < 4; jt++) {
                int col16 = nw * 4 + jt;   // this wave's column-16-group
                bf16x8 b = *(const bf16x8*)&ws[cur][(col16 * 16 + l16) * 128 + ((c0 ^ l16) << 3)];
                acc[0][jt] = __builtin_amdgcn_mfma_f32_16x16x32_bf16(a0, b, acc[0][jt], 0, 0, 0);
                acc[1][jt] = __builtin_amdgcn_mfma_f32_16x16x32_bf16(a1, b, acc[1][jt], 0, 0, 0);
            }
        }
        if (s + 2 <= 8) {   // 2-deep A prefetch into the slot just consumed
#pragma unroll
            for (int kc = 0; kc < 4; kc++) {
                int co = (kc * 4 + quad) * 8;
                aReg[cur][0][kc] = *(const uint4*)(aptr(nc0, s + 2) + co);
                aReg[cur][1][kc] = *(const uint4*)(aptr(nc1, s + 2) + co);
            }
        }
        __syncthreads();   // drains vmcnt -> W_{s+1} landed; all done reading ws[cur]
    }

#pragma unroll
    for (int tl = 0; tl < 2; tl++) {
#pragma unroll
        for (int reg = 0; reg < 4; reg++) {
            int node = base + mw * 32 + tl * 16 + quad * 4 + reg;
            if (node >= N_NODES) continue;
#pragma unroll
            for (int jt = 0; jt < 4; jt++) {
                int col = (nw * 4 + jt) * 16 + l16;
                float v = acc[tl][jt][reg] + bias1[col];
                h1b[(size_t)node * D + col] = (unsigned short)f2b(v);
            }
        }
    }
}

// ---- GraphConv agg: nbr[d] = sum h1b[src] over full in-edge range (16-lane subwave) ----
__global__ __launch_bounds__(256) void k_agg_nbr(const unsigned short* __restrict__ h1b,
                                                 const int* __restrict__ es1,
                                                 const int* __restrict__ seg_off,
                                                 unsigned short* __restrict__ nbr) {
    int t = threadIdx.x;
    int wave = t >> 6, lane = t & 63, sub = lane >> 4, l = lane & 15;
    int d = blockIdx.x * 16 + wave * 4 + sub;
    if (d >= N_NODES) return;
    int start = (d == 0) ? 0 : seg_off[d * R_REL - 1];
    int end = seg_off[d * R_REL + 7];
    float acc[8];
#pragma unroll
    for (int j = 0; j < 8; j++) acc[j] = 0.f;
    size_t loff = (size_t)l * 8;

    int pos = start;
    for (; pos + 4 <= end; pos += 4) {
        int i0 = es1[pos], i1 = es1[pos + 1], i2 = es1[pos + 2], i3 = es1[pos + 3];
        uint4 v0 = *(const uint4*)(h1b + (size_t)i0 * D + loff);
        uint4 v1 = *(const uint4*)(h1b + (size_t)i1 * D + loff);
        uint4 v2 = *(const uint4*)(h1b + (size_t)i2 * D + loff);
        uint4 v3 = *(const uint4*)(h1b + (size_t)i3 * D + loff);
        const uint32_t* w0 = (const uint32_t*)&v0;
        const uint32_t* w1 = (const uint32_t*)&v1;
        const uint32_t* w2 = (const uint32_t*)&v2;
        const uint32_t* w3 = (const uint32_t*)&v3;
#pragma unroll
        for (int q = 0; q < 4; q++) {
            acc[q * 2]     += b2f((uint16_t)w0[q]) + b2f((uint16_t)w1[q]) +
                              b2f((uint16_t)w2[q]) + b2f((uint16_t)w3[q]);
            acc[q * 2 + 1] += b2f((uint16_t)(w0[q] >> 16)) + b2f((uint16_t)(w1[q] >> 16)) +
                              b2f((uint16_t)(w2[q] >> 16)) + b2f((uint16_t)(w3[q] >> 16));
        }
    }
    for (; pos < end; pos++) {
        int i0 = es1[pos];
        uint4 v0 = *(const uint4*)(h1b + (size_t)i0 * D + loff);
        const uint32_t* w0 = (const uint32_t*)&v0;
#pragma unroll
        for (int q = 0; q < 4; q++) {
            acc[q * 2]     += b2f((uint16_t)w0[q]);
            acc[q * 2 + 1] += b2f((uint16_t)(w0[q] >> 16));
        }
    }

    union { uint4 u; unsigned short h[8]; } pk;
#pragma unroll
    for (int j = 0; j < 8; j++) pk.h[j] = (unsigned short)f2b(acc[j]);
    *(uint4*)(nbr + (size_t)d * D + loff) = pk.u;
}

// ---- epilogue GEMM v7: 512 thr (r5-proven widening), both W staged up-front
// via global_load_lds into ws[0]/ws[1] (64KB total), ONE barrier, no dbuf loop. ----
__global__ __launch_bounds__(512) void k_out2(const unsigned short* __restrict__ h1b,
                                              const unsigned short* __restrict__ nbr,
                                              const short* __restrict__ wroot_b,
                                              const short* __restrict__ wrel_b,
                                              const float* __restrict__ brel,
                                              float* __restrict__ out) {
    __shared__ short ws[2][128 * 128];
    int t = threadIdx.x;
    int wave = t >> 6, lane = t & 63, quad = lane >> 4, l16 = lane & 15;
    int mw = wave & 3, nw = wave >> 2;
    int base = blockIdx.x * 128;
    int n0 = base + mw * 32 + l16;
    int n1 = n0 + 16;
    int nc0 = n0 < N_NODES ? n0 : N_NODES - 1;
    int nc1 = n1 < N_NODES ? n1 : N_NODES - 1;

    // stage both weight matrices asynchronously (same swizzle scheme as k_h1_gemm)
#pragma unroll
    for (int i = 0; i < 4; i++) {
        int r0 = wave * 16 + i * 4;
        int row = r0 + quad;
        int so = row * D + ((l16 ^ (row & 15)) << 3);
        gload_lds16(wroot_b + so, &ws[0][r0 * 128]);
        gload_lds16(wrel_b + so, &ws[1][r0 * 128]);
    }

    uint4 a0[2][4], a1[2][4];   // [tile][kc]: pass0 = h1b@wroot^T, pass1 = nbr@wrel^T
#pragma unroll
    for (int kc = 0; kc < 4; kc++) {
        int co = (kc * 4 + quad) * 8;
        a0[0][kc] = *(const uint4*)(h1b + (size_t)nc0 * D + co);
        a0[1][kc] = *(const uint4*)(h1b + (size_t)nc1 * D + co);
        a1[0][kc] = *(const uint4*)(nbr + (size_t)nc0 * D + co);
        a1[1][kc] = *(const uint4*)(nbr + (size_t)nc1 * D + co);
    }
    __syncthreads();

    f32x4 acc[2][4];
#pragma unroll
    for (int tl = 0; tl < 2; tl++)
#pragma unroll
        for (int jt = 0; jt < 4; jt++) acc[tl][jt] = (f32x4){0.f, 0.f, 0.f, 0.f};

#pragma unroll
    for (int kc = 0; kc < 4; kc++) {
        int c0 = kc * 4 + quad;
        bf16x8 x0 = *(bf16x8*)&a0[0][kc];
        bf16x8 x1 = *(bf16x8*)&a0[1][kc];
#pragma unroll
        for (int jt = 0; jt < 4; jt++) {
            bf16x8 b = *(const bf16x8*)&ws[0][((nw * 4 + jt) * 16 + l16) * 128 + ((c0 ^ l16) << 3)];
            acc[0][jt] = __builtin_amdgcn_mfma_f32_16x16x32_bf16(x0, b, acc[0][jt], 0, 0, 0);
            acc[1][jt] = __builtin_amdgcn_mfma_f32_16x16x32_bf16(x1, b, acc[1][jt], 0, 0, 0);
        }
    }
#pragma unroll
    for (int kc = 0; kc < 4; kc++) {
        int c0 = kc * 4 + quad;
        bf16x8 x0 = *(bf16x8*)&a1[0][kc];
        bf16x8 x1 = *(bf16x8*)&a1[1][kc];
#pragma unroll
        for (int jt = 0; jt < 4; jt++) {
            bf16x8 b = *(const bf16x8*)&ws[1][((nw * 4 + jt) * 16 + l16) * 128 + ((c0 ^ l16) << 3)];
            acc[0][jt] = __builtin_amdgcn_mfma_f32_16x16x32_bf16(x0, b, acc[0][jt], 0, 0, 0);
            acc[1][jt] = __builtin_amdgcn_mfma_f32_16x16x32_bf16(x1, b, acc[1][jt], 0, 0, 0);
        }
    }

#pragma unroll
    for (int tl = 0; tl < 2; tl++) {
#pragma unroll
        for (int reg = 0; reg < 4; reg++) {
            int node = base + mw * 32 + tl * 16 + quad * 4 + reg;
            if (node >= N_NODES) continue;
#pragma unroll
            for (int jt = 0; jt < 4; jt++) {
                int col = (nw * 4 + jt) * 16 + l16;
                out[(size_t)node * D + col] = acc[tl][jt][reg] + brel[col];
            }
        }
    }
}

extern "C" void kernel_launch(void* const* d_in, const int* in_sizes, int n_in,
                              void* d_out, int out_size, void* d_ws, size_t ws_size,
                              hipStream_t stream) {
    const float* x     = (const float*)d_in[0];
    const int*   ei    = (const int*)d_in[1];
    const int*   et    = (const int*)d_in[2];
    const float* basis = (const float*)d_in[3];
    const float* comp  = (const float*)d_in[4];
    const float* root  = (const float*)d_in[5];
    const float* bias1 = (const float*)d_in[6];
    const float* wrel  = (const float*)d_in[7];
    const float* brel  = (const float*)d_in[8];
    const float* wroot = (const float*)d_in[9];
    float* out = (float*)d_out;
    const int* src = ei;
    const int* dst = ei + E_EDGES;

    char* p = (char*)d_ws;
    auto alloc = [&](size_t bytes) { char* q = p; p += (bytes + 255) & ~(size_t)255; return q; };
    short* wt      = (short*)alloc((size_t)9 * D * D * sizeof(short));
    short* wrel_b  = (short*)alloc(D * D * sizeof(short));
    short* wroot_b = (short*)alloc(D * D * sizeof(short));
    int*   cntr    = (int*)alloc((size_t)RN * sizeof(int));
    int*   seg_off = (int*)alloc((size_t)RN * sizeof(int));
    int*   es1     = (int*)alloc((size_t)(E_EDGES + 16) * sizeof(int));
    int*   bsum    = (int*)alloc(1024 * sizeof(int));
    unsigned short* xb  = (unsigned short*)alloc((size_t)N_NODES * D * sizeof(unsigned short));
    unsigned short* mx  = (unsigned short*)alloc((size_t)RN * D * sizeof(unsigned short));
    unsigned short* h1b = (unsigned short*)alloc((size_t)N_NODES * D * sizeof(unsigned short));
    unsigned short* nbr = xb;   // xb dead after k_h1_gemm; reuse for nbr

    hipMemsetAsync(cntr, 0, (size_t)RN * sizeof(int), stream);

    const int XB_N = N_NODES * D / 8;
    int nfront = (XB_N + E_EDGES + 9 * D * D + D * D + 255) / 256;
    k_front<<<nfront, 256, 0, stream>>>(x, xb, dst, et, cntr,
                                        basis, comp, root, wrel, wroot,
                                        wt, wrel_b, wroot_b);

    int nscan = (RN + 1023) / 1024;   // 391
    k_scan_a<<<nscan, 1024, 0, stream>>>(cntr, seg_off, bsum, RN);
    k_scan_a<<<1, 1024, 0, stream>>>(bsum, bsum, nullptr, nscan);
    k_scan_c<<<nscan, 1024, 0, stream>>>(seg_off, bsum, RN);

    k_bucket<<<(E_EDGES + 255) / 256, 256, 0, stream>>>(src, dst, et, seg_off, es1);

    k_aggmean<<<RN / 16, 256, 0, stream>>>(xb, es1, seg_off, mx);

    int nb2 = (N_NODES + 127) / 128;  // 391
    int na = (N_NODES + 15) / 16;     // 3125
    k_h1_gemm<<<nb2, 512, 0, stream>>>(mx, xb, wt, bias1, h1b);
    k_agg_nbr<<<na, 256, 0, stream>>>(h1b, es1, seg_off, nbr);
    k_out2<<<nb2, 512, 0, stream>>>(h1b, nbr, wroot_b, wrel_b, brel, out);
}

// Round 9
// 264.972 us; speedup vs baseline: 1.0917x; 1.0917x over previous
//
#include <hip/hip_runtime.h>
#include <stdint.h>

#define N_NODES 50000
#define E_EDGES 600000
#define D 128
#define R_REL 8
#define B_BASES 10
#define RN (R_REL * N_NODES)

typedef __attribute__((ext_vector_type(8))) short bf16x8;
typedef __attribute__((ext_vector_type(4))) float f32x4;

__device__ __forceinline__ short f2b(float f) {
    uint32_t u = __float_as_uint(f);
    u += 0x7fff + ((u >> 16) & 1);   // RNE
    return (short)(u >> 16);
}
__device__ __forceinline__ float b2f(uint16_t u) {
    return __uint_as_float((uint32_t)u << 16);
}

// LDS-only barrier: orders ds_read/ds_write across the workgroup WITHOUT
// draining vmcnt (__syncthreads emits s_waitcnt vmcnt(0) lgkmcnt(0) which
// retires the in-flight A-register prefetch every step — the r0-r8 floor).
// Global loads target registers only here; the compiler's own dependency
// waits cover their first use. sched_barrier(0) fences motion (rule #18).
__device__ __forceinline__ void lds_barrier() {
    __builtin_amdgcn_sched_barrier(0);
    asm volatile("s_waitcnt lgkmcnt(0)\n\ts_barrier" ::: "memory");
    __builtin_amdgcn_sched_barrier(0);
}

// ---- front: x->bf16 convert + (dst,rel) histogram + weight prep, one launch ----
__global__ __launch_bounds__(256) void k_front(const float* __restrict__ x,
                                               unsigned short* __restrict__ xb,
                                               const int* __restrict__ dst,
                                               const int* __restrict__ et,
                                               int* __restrict__ cntr,
                                               const float* __restrict__ basis,
                                               const float* __restrict__ comp,
                                               const float* __restrict__ root,
                                               const float* __restrict__ wrel,
                                               const float* __restrict__ wroot,
                                               short* __restrict__ wt,
                                               short* __restrict__ wrel_b,
                                               short* __restrict__ wroot_b) {
    const int XB_N = N_NODES * D / 8;   // 800000
    int tid = blockIdx.x * 256 + threadIdx.x;
    if (tid < XB_N) {
        const float4* s = (const float4*)x + (size_t)tid * 2;
        float4 v0 = s[0], v1 = s[1];
        union { uint4 u; unsigned short h[8]; } pk;
        pk.h[0] = (unsigned short)f2b(v0.x); pk.h[1] = (unsigned short)f2b(v0.y);
        pk.h[2] = (unsigned short)f2b(v0.z); pk.h[3] = (unsigned short)f2b(v0.w);
        pk.h[4] = (unsigned short)f2b(v1.x); pk.h[5] = (unsigned short)f2b(v1.y);
        pk.h[6] = (unsigned short)f2b(v1.z); pk.h[7] = (unsigned short)f2b(v1.w);
        ((uint4*)xb)[tid] = pk.u;
    } else if (tid < XB_N + E_EDGES) {
        int e = tid - XB_N;
        atomicAdd(&cntr[dst[e] * R_REL + et[e]], 1);
    } else {
        int t2 = tid - XB_N - E_EDGES;
        if (t2 < 9 * D * D) {
            int s = t2 >> 14;
            int rem = t2 & 16383;
            int j = rem >> 7, i = rem & 127;
            float v;
            if (s < 8) {
                v = 0.f;
#pragma unroll
                for (int b = 0; b < B_BASES; b++)
                    v += comp[s * B_BASES + b] * basis[b * D * D + i * D + j];
            } else {
                v = root[i * D + j];
            }
            wt[t2] = f2b(v);
        } else {
            int t3 = t2 - 9 * D * D;
            if (t3 < D * D) {
                wrel_b[t3]  = f2b(wrel[t3]);
                wroot_b[t3] = f2b(wroot[t3]);
            }
        }
    }
}

// ---- shuffle-based block scan (1024 thr); doubles as level-2 when bsum==null ----
__device__ __forceinline__ int wave_scan_incl(int v) {
    int lane = threadIdx.x & 63;
#pragma unroll
    for (int off = 1; off < 64; off <<= 1) {
        int n = __shfl_up(v, off, 64);
        if (lane >= off) v += n;
    }
    return v;
}

__global__ __launch_bounds__(1024) void k_scan_a(const int* __restrict__ in,
                                                 int* __restrict__ out,
                                                 int* __restrict__ bsum, int n) {
    __shared__ int wsum[16];
    int t = threadIdx.x, lane = t & 63, wid = t >> 6;
    int g = blockIdx.x * 1024 + t;
    int v = (g < n) ? in[g] : 0;
    int isc = wave_scan_incl(v);
    if (lane == 63) wsum[wid] = isc;
    __syncthreads();
    if (wid == 0) {
        int wv = (lane < 16) ? wsum[lane] : 0;
        int wsc = wave_scan_incl(wv);
        if (lane < 16) wsum[lane] = wsc - wv;
    }
    __syncthreads();
    if (g < n) out[g] = wsum[wid] + isc - v;
    if (t == 1023 && bsum) bsum[blockIdx.x] = wsum[15] + isc;
}

__global__ __launch_bounds__(1024) void k_scan_c(int* __restrict__ out,
                                                 const int* __restrict__ bsum, int n) {
    int g = blockIdx.x * 1024 + threadIdx.x;
    if (g < n) out[g] += bsum[blockIdx.x];
}

// ---- bucket: es1[pos] = src, sorted by (dst,rel); bumps seg_off to segment ENDS ----
__global__ __launch_bounds__(256) void k_bucket(const int* __restrict__ src,
                                                const int* __restrict__ dst,
                                                const int* __restrict__ et,
                                                int* __restrict__ seg_off,
                                                int* __restrict__ es1) {
    int e = blockIdx.x * 256 + threadIdx.x;
    if (e >= E_EDGES) return;
    int key = dst[e] * R_REL + et[e];
    int pos = atomicAdd(&seg_off[key], 1);
    es1[pos] = src[e];
}

// ---- per-(dst,rel) mean of xb[src] -> mx bf16 (node-major, r0-proven).
// One 16-lane subwave / segment; writes coalesce per consecutive k. ----
__global__ __launch_bounds__(256) void k_aggmean(const unsigned short* __restrict__ xb,
                                                 const int* __restrict__ es1,
                                                 const int* __restrict__ seg_off,
                                                 unsigned short* __restrict__ mx) {
    int t = threadIdx.x;
    int sw = t >> 4, l = t & 15;
    int k = blockIdx.x * 16 + sw;
    if (k >= RN) return;
    int start = (k == 0) ? 0 : seg_off[k - 1];
    int end = seg_off[k];
    float ax[8];
#pragma unroll
    for (int q = 0; q < 8; q++) ax[q] = 0.f;
    size_t loff = (size_t)l * 8;
    int pos = start;
    for (; pos + 2 <= end; pos += 2) {
        int s0 = es1[pos], s1 = es1[pos + 1];
        uint4 v0 = *(const uint4*)(xb + (size_t)s0 * D + loff);
        uint4 v1 = *(const uint4*)(xb + (size_t)s1 * D + loff);
        const uint32_t* w0 = (const uint32_t*)&v0;
        const uint32_t* w1 = (const uint32_t*)&v1;
#pragma unroll
        for (int q = 0; q < 4; q++) {
            ax[q * 2]     += b2f((uint16_t)w0[q]) + b2f((uint16_t)w1[q]);
            ax[q * 2 + 1] += b2f((uint16_t)(w0[q] >> 16)) + b2f((uint16_t)(w1[q] >> 16));
        }
    }
    if (pos < end) {
        int s0 = es1[pos];
        uint4 v0 = *(const uint4*)(xb + (size_t)s0 * D + loff);
        const uint32_t* w0 = (const uint32_t*)&v0;
#pragma unroll
        for (int q = 0; q < 4; q++) {
            ax[q * 2]     += b2f((uint16_t)w0[q]);
            ax[q * 2 + 1] += b2f((uint16_t)(w0[q] >> 16));
        }
    }
    float nm = (end > start) ? 1.f / (float)(end - start) : 0.f;
    union { uint4 u; unsigned short h[8]; } pk;
#pragma unroll
    for (int q = 0; q < 8; q++) pk.h[q] = (unsigned short)f2b(ax[q] * nm);
    *(uint4*)(mx + (size_t)k * D + loff) = pk.u;   // k*128 = d*1024 + r*128
}

// ---- h1 GEMM (r0 skeleton, M=32/wave, 4 waves, dbuf 64KB LDS) with LDS-only
// barriers: A-register prefetch stays in flight across steps instead of being
// drained by __syncthreads' vmcnt(0). Only the barrier implementation changed
// vs the proven r0 kernel (46us, VGPR 116, clean). ----
__global__ __launch_bounds__(256) void k_h1_gemm(const unsigned short* __restrict__ mx,
                                                 const unsigned short* __restrict__ xb,
                                                 const short* __restrict__ wt,
                                                 const float* __restrict__ bias1,
                                                 unsigned short* __restrict__ h1b) {
    __shared__ short ws[2][128 * 128];
    int t = threadIdx.x;
    int wave = t >> 6, lane = t & 63, quad = lane >> 4, l16 = lane & 15;
    int base = blockIdx.x * 128;
    int n0 = base + wave * 32 + l16;
    int n1 = n0 + 16;
    int nc0 = n0 < N_NODES ? n0 : N_NODES - 1;
    int nc1 = n1 < N_NODES ? n1 : N_NODES - 1;
    int ci0 = wave * 8;

    auto aptr = [&](int nc, int s) -> const unsigned short* {
        return (s < 8) ? mx + ((size_t)nc * 8 + s) * D : xb + (size_t)nc * D;
    };

    uint4 aReg[2][2][4];   // [parity][tile][kc]
    {
        uint4 b0[8];
#pragma unroll
        for (int i = 0; i < 8; i++) {
            int row = (ci0 + i) * 4 + quad;
            b0[i] = *(const uint4*)(wt + row * D + (l16 << 3));
        }
#pragma unroll
        for (int kc = 0; kc < 4; kc++) {
            int co = (kc * 4 + quad) * 8;
            aReg[0][0][kc] = *(const uint4*)(aptr(nc0, 0) + co);
            aReg[0][1][kc] = *(const uint4*)(aptr(nc1, 0) + co);
            aReg[1][0][kc] = *(const uint4*)(aptr(nc0, 1) + co);
            aReg[1][1][kc] = *(const uint4*)(aptr(nc1, 1) + co);
        }
#pragma unroll
        for (int i = 0; i < 8; i++) {
            int row = (ci0 + i) * 4 + quad;
            *(uint4*)&ws[0][row * 128 + ((l16 ^ (row & 15)) << 3)] = b0[i];
        }
    }
    lds_barrier();

    f32x4 acc[2][8];
#pragma unroll
    for (int tl = 0; tl < 2; tl++)
#pragma unroll
        for (int jt = 0; jt < 8; jt++) acc[tl][jt] = (f32x4){0.f, 0.f, 0.f, 0.f};

    for (int s = 0; s < 9; s++) {
        int cur = s & 1;
        uint4 bn[8];
        if (s + 1 < 9) {
            const short* wb = wt + (size_t)(s + 1) * D * D;
#pragma unroll
            for (int i = 0; i < 8; i++) {
                int row = (ci0 + i) * 4 + quad;
                bn[i] = *(const uint4*)(wb + row * D + (l16 << 3));
            }
        }
#pragma unroll
        for (int kc = 0; kc < 4; kc++) {
            int c0 = kc * 4 + quad;
            bf16x8 a0 = *(bf16x8*)&aReg[cur][0][kc];
            bf16x8 a1 = *(bf16x8*)&aReg[cur][1][kc];
#pragma unroll
            for (int jt = 0; jt < 8; jt++) {
                bf16x8 b = *(const bf16x8*)&ws[cur][(jt * 16 + l16) * 128 + ((c0 ^ l16) << 3)];
                acc[0][jt] = __builtin_amdgcn_mfma_f32_16x16x32_bf16(a0, b, acc[0][jt], 0, 0, 0);
                acc[1][jt] = __builtin_amdgcn_mfma_f32_16x16x32_bf16(a1, b, acc[1][jt], 0, 0, 0);
            }
        }
        if (s + 2 <= 8) {
#pragma unroll
            for (int kc = 0; kc < 4; kc++) {
                int co = (kc * 4 + quad) * 8;
                aReg[cur][0][kc] = *(const uint4*)(aptr(nc0, s + 2) + co);
                aReg[cur][1][kc] = *(const uint4*)(aptr(nc1, s + 2) + co);
            }
        }
        if (s + 1 < 9) {
#pragma unroll
            for (int i = 0; i < 8; i++) {
                int row = (ci0 + i) * 4 + quad;
                *(uint4*)&ws[cur ^ 1][row * 128 + ((l16 ^ (row & 15)) << 3)] = bn[i];
            }
        }
        lds_barrier();
    }

#pragma unroll
    for (int tl = 0; tl < 2; tl++) {
#pragma unroll
        for (int reg = 0; reg < 4; reg++) {
            int node = base + wave * 32 + tl * 16 + quad * 4 + reg;
            if (node >= N_NODES) continue;
#pragma unroll
            for (int jt = 0; jt < 8; jt++) {
                int col = jt * 16 + l16;
                float v = acc[tl][jt][reg] + bias1[col];
                h1b[(size_t)node * D + col] = (unsigned short)f2b(v);
            }
        }
    }
}

// ---- GraphConv agg: nbr[d] = sum h1b[src] over full in-edge range (16-lane subwave) ----
__global__ __launch_bounds__(256) void k_agg_nbr(const unsigned short* __restrict__ h1b,
                                                 const int* __restrict__ es1,
                                                 const int* __restrict__ seg_off,
                                                 unsigned short* __restrict__ nbr) {
    int t = threadIdx.x;
    int wave = t >> 6, lane = t & 63, sub = lane >> 4, l = lane & 15;
    int d = blockIdx.x * 16 + wave * 4 + sub;
    if (d >= N_NODES) return;
    int start = (d == 0) ? 0 : seg_off[d * R_REL - 1];
    int end = seg_off[d * R_REL + 7];
    float acc[8];
#pragma unroll
    for (int j = 0; j < 8; j++) acc[j] = 0.f;
    size_t loff = (size_t)l * 8;

    int pos = start;
    for (; pos + 4 <= end; pos += 4) {
        int i0 = es1[pos], i1 = es1[pos + 1], i2 = es1[pos + 2], i3 = es1[pos + 3];
        uint4 v0 = *(const uint4*)(h1b + (size_t)i0 * D + loff);
        uint4 v1 = *(const uint4*)(h1b + (size_t)i1 * D + loff);
        uint4 v2 = *(const uint4*)(h1b + (size_t)i2 * D + loff);
        uint4 v3 = *(const uint4*)(h1b + (size_t)i3 * D + loff);
        const uint32_t* w0 = (const uint32_t*)&v0;
        const uint32_t* w1 = (const uint32_t*)&v1;
        const uint32_t* w2 = (const uint32_t*)&v2;
        const uint32_t* w3 = (const uint32_t*)&v3;
#pragma unroll
        for (int q = 0; q < 4; q++) {
            acc[q * 2]     += b2f((uint16_t)w0[q]) + b2f((uint16_t)w1[q]) +
                              b2f((uint16_t)w2[q]) + b2f((uint16_t)w3[q]);
            acc[q * 2 + 1] += b2f((uint16_t)(w0[q] >> 16)) + b2f((uint16_t)(w1[q] >> 16)) +
                              b2f((uint16_t)(w2[q] >> 16)) + b2f((uint16_t)(w3[q] >> 16));
        }
    }
    for (; pos < end; pos++) {
        int i0 = es1[pos];
        uint4 v0 = *(const uint4*)(h1b + (size_t)i0 * D + loff);
        const uint32_t* w0 = (const uint32_t*)&v0;
#pragma unroll
        for (int q = 0; q < 4; q++) {
            acc[q * 2]     += b2f((uint16_t)w0[q]);
            acc[q * 2 + 1] += b2f((uint16_t)(w0[q] >> 16));
        }
    }

    union { uint4 u; unsigned short h[8]; } pk;
#pragma unroll
    for (int j = 0; j < 8; j++) pk.h[j] = (unsigned short)f2b(acc[j]);
    *(uint4*)(nbr + (size_t)d * D + loff) = pk.u;
}

// ---- epilogue GEMM, pipelined, M=32/wave: out = h1b@wroot^T + nbr@wrel^T + brel ----
__global__ __launch_bounds__(256) void k_out2(const unsigned short* __restrict__ h1b,
                                              const unsigned short* __restrict__ nbr,
                                              const short* __restrict__ wroot_b,
                                              const short* __restrict__ wrel_b,
                                              const float* __restrict__ brel,
                                              float* __restrict__ out) {
    __shared__ short ws[2][128 * 128];
    int t = threadIdx.x;
    int wave = t >> 6, lane = t & 63, quad = lane >> 4, l16 = lane & 15;
    int base = blockIdx.x * 128;
    int n0 = base + wave * 32 + l16;
    int n1 = n0 + 16;
    int nc0 = n0 < N_NODES ? n0 : N_NODES - 1;
    int nc1 = n1 < N_NODES ? n1 : N_NODES - 1;
    int ci0 = wave * 8;

    uint4 aReg[2][2][4];   // [pass][tile][kc]
    {
        uint4 b0[8];
#pragma unroll
        for (int i = 0; i < 8; i++) {
            int row = (ci0 + i) * 4 + quad;
            b0[i] = *(const uint4*)(wroot_b + row * D + (l16 << 3));
        }
#pragma unroll
        for (int kc = 0; kc < 4; kc++) {
            int co = (kc * 4 + quad) * 8;
            aReg[0][0][kc] = *(const uint4*)(h1b + (size_t)nc0 * D + co);
            aReg[0][1][kc] = *(const uint4*)(h1b + (size_t)nc1 * D + co);
            aReg[1][0][kc] = *(const uint4*)(nbr + (size_t)nc0 * D + co);
            aReg[1][1][kc] = *(const uint4*)(nbr + (size_t)nc1 * D + co);
        }
#pragma unroll
        for (int i = 0; i < 8; i++) {
            int row = (ci0 + i) * 4 + quad;
            *(uint4*)&ws[0][row * 128 + ((l16 ^ (row & 15)) << 3)] = b0[i];
        }
    }
    __syncthreads();

    f32x4 acc[2][8];
#pragma unroll
    for (int tl = 0; tl < 2; tl++)
#pragma unroll
        for (int jt = 0; jt < 8; jt++) acc[tl][jt] = (f32x4){0.f, 0.f, 0.f, 0.f};

#pragma unroll
    for (int s = 0; s < 2; s++) {
        int cur = s & 1;
        uint4 bn[8];
        if (s == 0) {
#pragma unroll
            for (int i = 0; i < 8; i++) {
                int row = (ci0 + i) * 4 + quad;
                bn[i] = *(const uint4*)(wrel_b + row * D + (l16 << 3));
            }
        }
#pragma unroll
        for (int kc = 0; kc < 4; kc++) {
            int c0 = kc * 4 + quad;
            bf16x8 a0 = *(bf16x8*)&aReg[cur][0][kc];
            bf16x8 a1 = *(bf16x8*)&aReg[cur][1][kc];
#pragma unroll
            for (int jt = 0; jt < 8; jt++) {
                bf16x8 b = *(const bf16x8*)&ws[cur][(jt * 16 + l16) * 128 + ((c0 ^ l16) << 3)];
                acc[0][jt] = __builtin_amdgcn_mfma_f32_16x16x32_bf16(a0, b, acc[0][jt], 0, 0, 0);
                acc[1][jt] = __builtin_amdgcn_mfma_f32_16x16x32_bf16(a1, b, acc[1][jt], 0, 0, 0);
            }
        }
        if (s == 0) {
#pragma unroll
            for (int i = 0; i < 8; i++) {
                int row = (ci0 + i) * 4 + quad;
                *(uint4*)&ws[1][row * 128 + ((l16 ^ (row & 15)) << 3)] = bn[i];
            }
            __syncthreads();
        }
    }

#pragma unroll
    for (int tl = 0; tl < 2; tl++) {
#pragma unroll
        for (int reg = 0; reg < 4; reg++) {
            int node = base + wave * 32 + tl * 16 + quad * 4 + reg;
            if (node >= N_NODES) continue;
#pragma unroll
            for (int jt = 0; jt < 8; jt++) {
                int col = jt * 16 + l16;
                out[(size_t)node * D + col] = acc[tl][jt][reg] + brel[col];
            }
        }
    }
}

extern "C" void kernel_launch(void* const* d_in, const int* in_sizes, int n_in,
                              void* d_out, int out_size, void* d_ws, size_t ws_size,
                              hipStream_t stream) {
    const float* x     = (const float*)d_in[0];
    const int*   ei    = (const int*)d_in[1];
    const int*   et    = (const int*)d_in[2];
    const float* basis = (const float*)d_in[3];
    const float* comp  = (const float*)d_in[4];
    const float* root  = (const float*)d_in[5];
    const float* bias1 = (const float*)d_in[6];
    const float* wrel  = (const float*)d_in[7];
    const float* brel  = (const float*)d_in[8];
    const float* wroot = (const float*)d_in[9];
    float* out = (float*)d_out;
    const int* src = ei;
    const int* dst = ei + E_EDGES;

    char* p = (char*)d_ws;
    auto alloc = [&](size_t bytes) { char* q = p; p += (bytes + 255) & ~(size_t)255; return q; };
    short* wt      = (short*)alloc((size_t)9 * D * D * sizeof(short));
    short* wrel_b  = (short*)alloc(D * D * sizeof(short));
    short* wroot_b = (short*)alloc(D * D * sizeof(short));
    int*   cntr    = (int*)alloc((size_t)RN * sizeof(int));
    int*   seg_off = (int*)alloc((size_t)RN * sizeof(int));
    int*   es1     = (int*)alloc((size_t)(E_EDGES + 16) * sizeof(int));
    int*   bsum    = (int*)alloc(1024 * sizeof(int));
    unsigned short* xb  = (unsigned short*)alloc((size_t)N_NODES * D * sizeof(unsigned short));
    unsigned short* mx  = (unsigned short*)alloc((size_t)RN * D * sizeof(unsigned short));
    unsigned short* h1b = (unsigned short*)alloc((size_t)N_NODES * D * sizeof(unsigned short));
    unsigned short* nbr = xb;   // xb dead after k_h1_gemm; reuse for nbr

    hipMemsetAsync(cntr, 0, (size_t)RN * sizeof(int), stream);

    const int XB_N = N_NODES * D / 8;
    int nfront = (XB_N + E_EDGES + 9 * D * D + D * D + 255) / 256;
    k_front<<<nfront, 256, 0, stream>>>(x, xb, dst, et, cntr,
                                        basis, comp, root, wrel, wroot,
                                        wt, wrel_b, wroot_b);

    int nscan = (RN + 1023) / 1024;   // 391
    k_scan_a<<<nscan, 1024, 0, stream>>>(cntr, seg_off, bsum, RN);
    k_scan_a<<<1, 1024, 0, stream>>>(bsum, bsum, nullptr, nscan);
    k_scan_c<<<nscan, 1024, 0, stream>>>(seg_off, bsum, RN);

    k_bucket<<<(E_EDGES + 255) / 256, 256, 0, stream>>>(src, dst, et, seg_off, es1);

    k_aggmean<<<RN / 16, 256, 0, stream>>>(xb, es1, seg_off, mx);

    int nb2 = (N_NODES + 127) / 128;  // 391
    int na = (N_NODES + 15) / 16;     // 3125
    k_h1_gemm<<<nb2, 256, 0, stream>>>(mx, xb, wt, bias1, h1b);
    k_agg_nbr<<<na, 256, 0, stream>>>(h1b, es1, seg_off, nbr);
    k_out2<<<nb2, 256, 0, stream>>>(h1b, nbr, wroot_b, wrel_b, brel, out);
}